// Round 9
// baseline (348.536 us; speedup 1.0000x reference)
//
#include <hip/hip_runtime.h>
#include <cstdint>

// MTNN: static MLP + dyn proj + biRNN(relu) + routed per-trial dot.
// B=512,T=200,SI=100,DI=68,HS=256,HD=128,D=512,K=1. fp32 in, fp32 out.
// R17 (passed, 299us): k_dxw operand-swap -> vector epilogues, off top-5.
// R18: k_scan dual-direction interleave. fwd/bwd chains are independent ->
// one block (16 rows, 4 waves) runs BOTH: per step 16 MFMAs/wave in 4
// independent chains; the barrier+LDS H-exchange (half the old critical
// path) is paid ONCE per two dir-steps. Also: per-wave routed-dot partials
// stored directly (acc[w][b][t]); k_final sums 4+4 -> no pxch, no wave0
// serial reduce gating the barrier.
constexpr int B = 512, T = 200, SI = 100, DI = 68, HS = 256, HD = 128, D = 512;
constexpr int BT = B * T;   // 102400

typedef __attribute__((ext_vector_type(8))) short short8;       // 8 bf16
typedef __attribute__((ext_vector_type(4))) float floatx4;      // MFMA C/D
typedef _Float16 half8 __attribute__((ext_vector_type(8)));     // 8 fp16
typedef _Float16 half2t __attribute__((ext_vector_type(2)));    // fp16 pair
typedef unsigned int uint2v __attribute__((ext_vector_type(2)));
typedef unsigned int uint4v __attribute__((ext_vector_type(4)));

#define DEV __device__ __forceinline__

DEV unsigned short f2bf(float f) {
    unsigned int x = __builtin_bit_cast(unsigned int, f);
    x += 0x7fffu + ((x >> 16) & 1u);   // RNE
    return (unsigned short)(x >> 16);
}
DEV unsigned int pkbf(float a, float b) {   // two bf16 in one dword
    return (unsigned int)f2bf(a) | ((unsigned int)f2bf(b) << 16);
}
DEV unsigned short f2h(float f) {
    return __builtin_bit_cast(unsigned short, (_Float16)f);
}
DEV half2t u2h2(unsigned int u) { return __builtin_bit_cast(half2t, u); }
DEV unsigned int pkh(float a, float b) {
    return __builtin_bit_cast(unsigned int, __builtin_amdgcn_cvt_pkrtz(a, b));
}
// gfx950 lane swaps (VALU). After p32: a=[a.lo,b.lo], b=[a.hi,b.hi].
// After p16 (per 32-half): a=[a.q0,b.q0|a.q2,b.q2], b=[a.q1,b.q1|a.q3,b.q3].
#if __has_builtin(__builtin_amdgcn_permlane32_swap) && __has_builtin(__builtin_amdgcn_permlane16_swap)
DEV void pl32swap(unsigned int& a, unsigned int& b) {
    uint2v r = __builtin_amdgcn_permlane32_swap(a, b, false, false);
    a = r[0]; b = r[1];
}
DEV void pl16swap(unsigned int& a, unsigned int& b) {
    uint2v r = __builtin_amdgcn_permlane16_swap(a, b, false, false);
    a = r[0]; b = r[1];
}
#else
DEV void pl32swap(unsigned int& a, unsigned int& b) {
    unsigned int na, nb;
    asm("v_mov_b32 %0, %2\n\t"
        "v_mov_b32 %1, %3\n\t"
        "v_permlane32_swap_b32 %0, %1"
        : "=&v"(na), "=&v"(nb) : "v"(a), "v"(b));
    a = na; b = nb;
}
DEV void pl16swap(unsigned int& a, unsigned int& b) {
    unsigned int na, nb;
    asm("v_mov_b32 %0, %2\n\t"
        "v_mov_b32 %1, %3\n\t"
        "v_permlane16_swap_b32 %0, %1"
        : "=&v"(na), "=&v"(nb) : "v"(a), "v"(b));
    a = na; b = nb;
}
#endif

// ---------------- K0: one-time weight conversion ----------------------------
// wdyn_bf[128][96] bf16 (zero-pad K 68->96) | wih_bf[2][128][128] bf16 |
// whh_h[2][128][128] fp16 | bsum[2][128] f32 (b_ih+b_hh)
__global__ __launch_bounds__(256) void k_prep(
    const float* __restrict__ wdyn,
    const float* __restrict__ wihf, const float* __restrict__ wihb,
    const float* __restrict__ whhf, const float* __restrict__ whhb,
    const float* __restrict__ bihf, const float* __restrict__ bhhf,
    const float* __restrict__ bihb, const float* __restrict__ bhhb,
    unsigned short* __restrict__ wdyn_bf, unsigned short* __restrict__ wih_bf,
    unsigned short* __restrict__ whh_h, float* __restrict__ bsum)
{
    int gid = blockIdx.x * 256 + threadIdx.x, gs = gridDim.x * 256;
    for (int i = gid; i < HD * 96; i += gs) {
        int r = i / 96, c = i - r * 96;
        wdyn_bf[i] = (c < DI) ? f2bf(wdyn[r * DI + c]) : 0;
    }
    for (int i = gid; i < 2 * HD * HD; i += gs) {
        const float* src = (i < HD * HD) ? wihf : wihb;
        wih_bf[i] = f2bf(src[i & (HD * HD - 1)]);
    }
    for (int i = gid; i < 2 * HD * HD; i += gs) {
        const float* src = (i < HD * HD) ? whhf : whhb;
        whh_h[i] = f2h(src[i & (HD * HD - 1)]);
    }
    for (int i = gid; i < 2 * HD; i += gs) {
        int z = i >> 7, n = i & (HD - 1);
        bsum[i] = z ? (bihb[n] + bhhb[n]) : (bihf[n] + bhhf[n]);
    }
}

// ---------------- K1: static branch + static segment of routed dot ----------
__global__ __launch_bounds__(256) void k_static(
    const float* __restrict__ xs_g, const float* __restrict__ w1,
    const float* __restrict__ b1, const float* __restrict__ w2,
    const float* __restrict__ b2, const int* __restrict__ norder,
    const float* __restrict__ nw, const float* __restrict__ nb,
    float* __restrict__ statd)
{
    __shared__ __align__(16) float xs[SI];
    __shared__ __align__(16) float s1[HS];
    __shared__ __align__(16) float red[256];
    int b = blockIdx.x, t = threadIdx.x;
    if (t < SI) xs[t] = xs_g[b * SI + t];
    __syncthreads();
    float a = b1[t];
    const float4* w = (const float4*)(w1 + t * SI);
    const float4* xp4 = (const float4*)xs;
    #pragma unroll
    for (int i = 0; i < SI / 4; ++i) {
        float4 ww = w[i]; float4 xx = xp4[i];
        a += xx.x * ww.x + xx.y * ww.y + xx.z * ww.z + xx.w * ww.w;
    }
    s1[t] = fmaxf(a, 0.f);
    __syncthreads();
    float a2 = b2[t];
    const float4* w2p = (const float4*)(w2 + t * HS);
    const float4* s1p = (const float4*)s1;
    #pragma unroll 8
    for (int i = 0; i < HS / 4; ++i) {
        float4 ww = w2p[i]; float4 s = s1p[i];
        a2 += s.x * ww.x + s.y * ww.y + s.z * ww.z + s.w * ww.w;
    }
    float sv = fmaxf(a2, 0.f);
    int n = norder[b];
    red[t] = sv * nw[(size_t)n * D + t];
    __syncthreads();
    for (int s = 128; s > 0; s >>= 1) {
        if (t < s) red[t] += red[t + s];
        __syncthreads();
    }
    if (t == 0) statd[b] = red[0] + nb[n];
}

// ---------------- K2: d + ih-projection via MFMA (operand-swapped) ----------
// A=weight rows n, B=activation rows batch -> C/D lane (ln,q) holds
// out[batch=w*16+ln][n=j*16+q*4+r], r=0..3 -> vector epilogues.
__global__ __launch_bounds__(256) void k_dxw(
    const float* __restrict__ xd,
    const unsigned short* __restrict__ wdyn_bf, const float* __restrict__ bdyn,
    const unsigned short* __restrict__ wih_bf, const float* __restrict__ bsum,
    unsigned short* __restrict__ xw)
{
    __shared__ __align__(16) unsigned short xb[64][104];  // x bf16, K 0..95 (+pad)
    __shared__ __align__(16) unsigned short dl[64][136];  // d bf16, 128 cols (+pad)
    int tid = threadIdx.x;
    int R0 = blockIdx.x * 64;
    // zero xb (vectorized 16B)
    for (int i = tid; i < 64 * 104 / 8; i += 256)
        ((uint4v*)xb)[i] = uint4v{0u, 0u, 0u, 0u};
    __syncthreads();
    // stage x: float4 loads, packed-bf16 b64 LDS writes (17 float4 per row)
    for (int i = tid; i < 64 * 17; i += 256) {
        int r = i / 17, c = i - r * 17;
        float4 v = *(const float4*)(xd + (size_t)(R0 + r) * DI + c * 4);
        uint2 pk;
        pk.x = pkbf(v.x, v.y);
        pk.y = pkbf(v.z, v.w);
        *(uint2*)&xb[r][c * 4] = pk;
    }
    __syncthreads();

    int lane = tid & 63, w = tid >> 6;
    int ln = lane & 15, q = lane >> 4;

    // ---- P2: A=wdyn[n][k], B=x[batch][k] ----
    short8 xf[3];
    #pragma unroll
    for (int c = 0; c < 3; ++c)
        xf[c] = *(const short8*)&xb[w * 16 + ln][c * 32 + q * 8];
    #pragma unroll
    for (int j = 0; j < 8; ++j) {
        floatx4 a = {0.f, 0.f, 0.f, 0.f};
        #pragma unroll
        for (int c = 0; c < 3; ++c) {
            short8 wf = *(const short8*)(wdyn_bf + (size_t)(j * 16 + ln) * 96 + c * 32 + q * 8);
            a = __builtin_amdgcn_mfma_f32_16x16x32_bf16(wf, xf[c], a, 0, 0, 0);
        }
        float4 bd4 = *(const float4*)(bdyn + j * 16 + q * 4);
        uint2 pk;
        pk.x = pkbf(fmaxf(a[0] + bd4.x, 0.f), fmaxf(a[1] + bd4.y, 0.f));
        pk.y = pkbf(fmaxf(a[2] + bd4.z, 0.f), fmaxf(a[3] + bd4.w, 0.f));
        *(uint2*)&dl[w * 16 + ln][j * 16 + q * 4] = pk;   // d[batch][n..n+3]
    }
    __syncthreads();

    // ---- P3 (both directions): A=wih[n][k], B=d[batch][k] ----
    short8 df[4];
    #pragma unroll
    for (int c = 0; c < 4; ++c)
        df[c] = *(const short8*)&dl[w * 16 + ln][c * 32 + q * 8];
    #pragma unroll
    for (int z = 0; z < 2; ++z) {
        const unsigned short* wih = wih_bf + (size_t)z * HD * HD;
        unsigned short* outp = xw + (size_t)z * BT * HD;
        int row = R0 + w * 16 + ln;
        #pragma unroll
        for (int j = 0; j < 8; ++j) {
            floatx4 a = {0.f, 0.f, 0.f, 0.f};
            #pragma unroll
            for (int c = 0; c < 4; ++c) {
                short8 wf = *(const short8*)(wih + (size_t)(j * 16 + ln) * HD + c * 32 + q * 8);
                a = __builtin_amdgcn_mfma_f32_16x16x32_bf16(wf, df[c], a, 0, 0, 0);
            }
            float4 b4 = *(const float4*)(bsum + z * HD + j * 16 + q * 4);
            uint2 hp;
            hp.x = (unsigned int)f2h(a[0] + b4.x) | ((unsigned int)f2h(a[1] + b4.y) << 16);
            hp.y = (unsigned int)f2h(a[2] + b4.z) | ((unsigned int)f2h(a[3] + b4.w) << 16);
            *(uint2*)(outp + (size_t)row * HD + j * 16 + q * 4) = hp;
        }
    }
}

// ---------------- K3: MFMA recurrence, 4-wave o-split, dual-dir -------------
// 32 blocks x 256 thr (4 waves). Block owns 16 batch rows, runs BOTH dirs.
// Wave w: o-tiles j=2w,2w+1 for fwd AND bwd -> 16 MFMAs/step in 4
// independent chains; one barrier+exchange serves two dir-steps. Routed-dot
// partials stored per-wave to acc[w][b][t]; k_final sums 4+4.
__global__ __launch_bounds__(256, 1) void k_scan(
    const unsigned short* __restrict__ xw, const unsigned short* __restrict__ whh_h,
    const int* __restrict__ norder, const float* __restrict__ nw,
    float* __restrict__ accf, float* __restrict__ accb)
{
    __shared__ __align__(16) uint4v hxch[2][2][4][64];  // [parity][dir][chunk][lane]

    int tid = threadIdx.x, w = tid >> 6, l = tid & 63, ln = l & 15, q = l >> 4;
    int b0 = blockIdx.x * 16;
    int j0 = 2 * w;

    // A-frags both dirs: Whh[d][o=(j0+jj)*16+ln][k=c*32+q*8..+7]
    half8 wfr[2][2][4];
    #pragma unroll
    for (int d = 0; d < 2; ++d)
        #pragma unroll
        for (int jj = 0; jj < 2; ++jj)
            #pragma unroll
            for (int c = 0; c < 4; ++c)
                wfr[d][jj][c] = *(const half8*)(whh_h + (size_t)d * HD * HD +
                    (size_t)((j0 + jj) * 16 + ln) * HD + c * 32 + q * 8);

    // routed weights, both dirs (segments HS and HS+HD of nw row)
    int nrow = norder[b0 + ln];
    float4 wnl[2][2];
    #pragma unroll
    for (int d = 0; d < 2; ++d)
        #pragma unroll
        for (int jj = 0; jj < 2; ++jj)
            wnl[d][jj] = *(const float4*)(nw + (size_t)nrow * D + (d ? HS + HD : HS) +
                                          (j0 + jj) * 16 + q * 4);

    half8 hfF[4], hfB[4];
    uint4v zz = {0u, 0u, 0u, 0u};
    #pragma unroll
    for (int c = 0; c < 4; ++c) {
        hfF[c] = __builtin_bit_cast(half8, zz);
        hfB[c] = __builtin_bit_cast(half8, zz);
    }

    const unsigned short* xpF = xw + ((size_t)(b0 + ln) * T) * HD;
    const unsigned short* xpB = xw + ((size_t)BT + (size_t)(b0 + ln) * T) * HD;
    float* accpF = accf + (size_t)w * BT + (size_t)(b0 + ln) * T;
    float* accpB = accb + (size_t)w * BT + (size_t)(b0 + ln) * T;

    uint2 xF0[2], xF1[2], xF2[2], xF3[2];
    uint2 xB0[2], xB1[2], xB2[2], xB3[2];
    auto ld = [&](uint2 (&xF)[2], uint2 (&xB)[2], int idx) {
        const unsigned short* ppF = xpF + (size_t)idx * HD;
        const unsigned short* ppB = xpB + (size_t)(T - 1 - idx) * HD;
        #pragma unroll
        for (int jj = 0; jj < 2; ++jj) {
            xF[jj] = *(const uint2*)(ppF + (j0 + jj) * 16 + q * 4);
            xB[jj] = *(const uint2*)(ppB + (j0 + jj) * 16 + q * 4);
        }
    };
    auto step = [&](uint2 (&xF)[2], uint2 (&xB)[2], int idx) {
        int tF = idx, tB = T - 1 - idx;
        int par = idx & 1;
        floatx4 aF[2], aB[2];
        #pragma unroll
        for (int jj = 0; jj < 2; ++jj) {
            half2t lo = u2h2(xF[jj].x), hi = u2h2(xF[jj].y);
            aF[jj] = floatx4{(float)lo[0], (float)lo[1], (float)hi[0], (float)hi[1]};
            half2t lo2 = u2h2(xB[jj].x), hi2 = u2h2(xB[jj].y);
            aB[jj] = floatx4{(float)lo2[0], (float)lo2[1], (float)hi2[0], (float)hi2[1]};
        }
        // 16 MFMAs: cc-major, 4 independent chains (F0,F1,B0,B1)
        #pragma unroll
        for (int cc = 0; cc < 4; ++cc) {
            #pragma unroll
            for (int jj = 0; jj < 2; ++jj)
                aF[jj] = __builtin_amdgcn_mfma_f32_16x16x32_f16(wfr[0][jj][cc], hfF[cc], aF[jj], 0, 0, 0);
            #pragma unroll
            for (int jj = 0; jj < 2; ++jj)
                aB[jj] = __builtin_amdgcn_mfma_f32_16x16x32_f16(wfr[1][jj][cc], hfB[cc], aB[jj], 0, 0, 0);
        }
        // epilogues: relu + pack + partial routed dot, per dir
        uint2 hpF[2], hpB[2];
        float pF = 0.f, pB = 0.f;
        #pragma unroll
        for (int jj = 0; jj < 2; ++jj) {
            float r0 = fmaxf(aF[jj][0], 0.f), r1 = fmaxf(aF[jj][1], 0.f);
            float r2 = fmaxf(aF[jj][2], 0.f), r3 = fmaxf(aF[jj][3], 0.f);
            hpF[jj].x = pkh(r0, r1); hpF[jj].y = pkh(r2, r3);
            float4 wn4 = wnl[0][jj];
            pF += r0 * wn4.x + r1 * wn4.y + r2 * wn4.z + r3 * wn4.w;
            float s0 = fmaxf(aB[jj][0], 0.f), s1 = fmaxf(aB[jj][1], 0.f);
            float s2 = fmaxf(aB[jj][2], 0.f), s3 = fmaxf(aB[jj][3], 0.f);
            hpB[jj].x = pkh(s0, s1); hpB[jj].y = pkh(s2, s3);
            float4 wm4 = wnl[1][jj];
            pB += s0 * wm4.x + s1 * wm4.y + s2 * wm4.z + s3 * wm4.w;
        }
        // next-step B-frag chunk w, per dir (permlane pair construction)
        {
            unsigned int ax = hpF[0].x, bx = hpF[1].x;
            pl32swap(ax, bx); pl16swap(ax, bx);
            unsigned int ay = hpF[0].y, by = hpF[1].y;
            pl32swap(ay, by); pl16swap(ay, by);
            hxch[par][0][w][l] = uint4v{ax, ay, bx, by};
        }
        {
            unsigned int ax = hpB[0].x, bx = hpB[1].x;
            pl32swap(ax, bx); pl16swap(ax, bx);
            unsigned int ay = hpB[0].y, by = hpB[1].y;
            pl32swap(ay, by); pl16swap(ay, by);
            hxch[par][1][w][l] = uint4v{ax, ay, bx, by};
        }
        // intra-wave q-reduce of partials; store per-wave slice (no xchg)
        unsigned int pa = __builtin_bit_cast(unsigned int, pF), pb = pa;
        pl32swap(pa, pb);
        float ps = __builtin_bit_cast(float, pa) + __builtin_bit_cast(float, pb);
        unsigned int pc = __builtin_bit_cast(unsigned int, ps), pd = pc;
        pl16swap(pc, pd);
        float ptF = __builtin_bit_cast(float, pc) + __builtin_bit_cast(float, pd);
        unsigned int qa = __builtin_bit_cast(unsigned int, pB), qb = qa;
        pl32swap(qa, qb);
        float qs = __builtin_bit_cast(float, qa) + __builtin_bit_cast(float, qb);
        unsigned int qc = __builtin_bit_cast(unsigned int, qs), qd = qc;
        pl16swap(qc, qd);
        float ptB = __builtin_bit_cast(float, qc) + __builtin_bit_cast(float, qd);
        if (l < 16) {
            accpF[tF] = ptF;
            accpB[tB] = ptB;
        }
        // exchange: drain own DS writes, raw barrier (NO vmcnt drain)
        asm volatile("s_waitcnt lgkmcnt(0)" ::: "memory");
        __builtin_amdgcn_sched_barrier(0);
        __builtin_amdgcn_s_barrier();
        __builtin_amdgcn_sched_barrier(0);
        #pragma unroll
        for (int c = 0; c < 4; ++c) {
            hfF[c] = __builtin_bit_cast(half8, hxch[par][0][c][l]);
            hfB[c] = __builtin_bit_cast(half8, hxch[par][1][c][l]);
        }
    };

    ld(xF0, xB0, 0); ld(xF1, xB1, 1); ld(xF2, xB2, 2); ld(xF3, xB3, 3);
    for (int c = 0; c < T / 4 - 1; ++c) {
        int i0 = c * 4;
        step(xF0, xB0, i0);     ld(xF0, xB0, i0 + 4);
        step(xF1, xB1, i0 + 1); ld(xF1, xB1, i0 + 5);
        step(xF2, xB2, i0 + 2); ld(xF2, xB2, i0 + 6);
        step(xF3, xB3, i0 + 3); ld(xF3, xB3, i0 + 7);
    }
    step(xF0, xB0, T - 4);
    step(xF1, xB1, T - 3);
    step(xF2, xB2, T - 2);
    step(xF3, xB3, T - 1);
}

// ---------------- K4: out = relu(statd + sum of 4+4 partials) -> FP32 -------
__global__ __launch_bounds__(256) void k_final(
    const float* __restrict__ statd, const float* __restrict__ accf,
    const float* __restrict__ accb, float* __restrict__ out)
{
    int idx = blockIdx.x * 256 + threadIdx.x;
    if (idx < BT) {
        int b = idx / T;
        float s = statd[b];
        #pragma unroll
        for (int w = 0; w < 4; ++w)
            s += accf[(size_t)w * BT + idx] + accb[(size_t)w * BT + idx];
        out[idx] = fmaxf(s, 0.f);
    }
}

extern "C" void kernel_launch(void* const* d_in, const int* in_sizes, int n_in,
                              void* d_out, int out_size, void* d_ws, size_t ws_size,
                              hipStream_t stream)
{
    const float* x_static  = (const float*)d_in[0];
    const float* x_dynamic = (const float*)d_in[1];
    const int*   norder    = (const int*)d_in[2];
    const float* w_s1   = (const float*)d_in[3];
    const float* b_s1   = (const float*)d_in[4];
    const float* w_s2   = (const float*)d_in[5];
    const float* b_s2   = (const float*)d_in[6];
    const float* w_dyn  = (const float*)d_in[7];
    const float* b_dyn  = (const float*)d_in[8];
    const float* w_ih_f = (const float*)d_in[9];
    const float* w_hh_f = (const float*)d_in[10];
    const float* b_ih_f = (const float*)d_in[11];
    const float* b_hh_f = (const float*)d_in[12];
    const float* w_ih_b = (const float*)d_in[13];
    const float* w_hh_b = (const float*)d_in[14];
    const float* b_ih_b = (const float*)d_in[15];
    const float* b_hh_b = (const float*)d_in[16];
    const float* nw     = (const float*)d_in[17];
    const float* nb     = (const float*)d_in[18];
    float* out = (float*)d_out;

    // ws: statd 2KB | accf 4*BT*4 | accb 4*BT*4 | xw fp16 52.4MB | prepped wts
    char* ws = (char*)d_ws;
    float* statd = (float*)ws;
    float* accf  = (float*)(ws + 2048);
    float* accb  = (float*)(ws + 2048 + (size_t)4 * BT * 4);
    unsigned short* xw = (unsigned short*)(ws + 2048 + (size_t)8 * BT * 4);
    size_t xw_bytes = (size_t)2 * BT * HD * 2;   // 52.4 MB
    unsigned short* wdyn_bf = (unsigned short*)(ws + 2048 + (size_t)8 * BT * 4 + xw_bytes);
    unsigned short* wih_bf  = wdyn_bf + HD * 96;
    unsigned short* whh_h   = wih_bf + 2 * HD * HD;
    float* bsum = (float*)(whh_h + 2 * HD * HD);

    hipLaunchKernelGGL(k_prep, dim3(64), dim3(256), 0, stream,
                       w_dyn, w_ih_f, w_ih_b, w_hh_f, w_hh_b,
                       b_ih_f, b_hh_f, b_ih_b, b_hh_b,
                       wdyn_bf, wih_bf, whh_h, bsum);
    hipLaunchKernelGGL(k_static, dim3(B), dim3(256), 0, stream,
                       x_static, w_s1, b_s1, w_s2, b_s2, norder, nw, nb, statd);
    hipLaunchKernelGGL(k_dxw, dim3(BT / 64), dim3(256), 0, stream,
                       x_dynamic, wdyn_bf, b_dyn, wih_bf, bsum, xw);
    hipLaunchKernelGGL(k_scan, dim3(32), dim3(256), 0, stream,
                       xw, whh_h, norder, nw, accf, accb);
    hipLaunchKernelGGL(k_final, dim3((BT + 255) / 256), dim3(256), 0, stream,
                       statd, accf, accb, out);
}

// Round 10
// 278.205 us; speedup vs baseline: 1.2528x; 1.2528x over previous
//
#include <hip/hip_runtime.h>
#include <cstdint>

// MTNN: static MLP + dyn proj + biRNN(relu) + routed per-trial dot.
// B=512,T=200,SI=100,DI=68,HS=256,HD=128,D=512,K=1. fp32 in, fp32 out.
// R16: 4-wave o-split, 8 MFMA/wave/step -> k_scan 88.6us (1063 cyc/step).
// R18: dual-dir 16 MFMA/wave/step -> 150us REGRESSION. Measured twice:
// recurrence wall time ~ per-wave MFMAs per step; barrier is the cheaper
// resource. -> R19: split MORE. 64 blocks x 8 waves (512thr), 1 o-tile per
// wave = 4 MFMAs/step as 2 independent K-split depth-2 chains (+f32x4 add).
// Handoff without permlanes: producer lane (ln,q) of wave w holds k =
// w*16+q*4+{0..3} = exactly words 2(q&1),+1 of B-frag chunk c=w>>1 quadrant
// q'=2(w&1)+(q>>1) -> ONE ds_write_b64 per lane into hxch, raw s_barrier
// (no vmcnt drain), 4x ds_read_b128. Per-wave routed partials to
// acc[w][b][t]; k_final sums 8+8.
constexpr int B = 512, T = 200, SI = 100, DI = 68, HS = 256, HD = 128, D = 512;
constexpr int BT = B * T;   // 102400

typedef __attribute__((ext_vector_type(8))) short short8;       // 8 bf16
typedef __attribute__((ext_vector_type(4))) float floatx4;      // MFMA C/D
typedef _Float16 half8 __attribute__((ext_vector_type(8)));     // 8 fp16
typedef _Float16 half2t __attribute__((ext_vector_type(2)));    // fp16 pair
typedef unsigned int uint2v __attribute__((ext_vector_type(2)));
typedef unsigned int uint4v __attribute__((ext_vector_type(4)));

#define DEV __device__ __forceinline__

DEV unsigned short f2bf(float f) {
    unsigned int x = __builtin_bit_cast(unsigned int, f);
    x += 0x7fffu + ((x >> 16) & 1u);   // RNE
    return (unsigned short)(x >> 16);
}
DEV unsigned int pkbf(float a, float b) {   // two bf16 in one dword
    return (unsigned int)f2bf(a) | ((unsigned int)f2bf(b) << 16);
}
DEV unsigned short f2h(float f) {
    return __builtin_bit_cast(unsigned short, (_Float16)f);
}
DEV half2t u2h2(unsigned int u) { return __builtin_bit_cast(half2t, u); }
DEV unsigned int pkh(float a, float b) {
    return __builtin_bit_cast(unsigned int, __builtin_amdgcn_cvt_pkrtz(a, b));
}
// gfx950 lane swaps (VALU), builtin form (SSA, no RA-coalescing hazard).
#if __has_builtin(__builtin_amdgcn_permlane32_swap) && __has_builtin(__builtin_amdgcn_permlane16_swap)
DEV void pl32swap(unsigned int& a, unsigned int& b) {
    uint2v r = __builtin_amdgcn_permlane32_swap(a, b, false, false);
    a = r[0]; b = r[1];
}
DEV void pl16swap(unsigned int& a, unsigned int& b) {
    uint2v r = __builtin_amdgcn_permlane16_swap(a, b, false, false);
    a = r[0]; b = r[1];
}
#else
DEV void pl32swap(unsigned int& a, unsigned int& b) {
    unsigned int na, nb;
    asm("v_mov_b32 %0, %2\n\t"
        "v_mov_b32 %1, %3\n\t"
        "v_permlane32_swap_b32 %0, %1"
        : "=&v"(na), "=&v"(nb) : "v"(a), "v"(b));
    a = na; b = nb;
}
DEV void pl16swap(unsigned int& a, unsigned int& b) {
    unsigned int na, nb;
    asm("v_mov_b32 %0, %2\n\t"
        "v_mov_b32 %1, %3\n\t"
        "v_permlane16_swap_b32 %0, %1"
        : "=&v"(na), "=&v"(nb) : "v"(a), "v"(b));
    a = na; b = nb;
}
#endif

// ---------------- K0: one-time weight conversion ----------------------------
// wdyn_bf[128][96] bf16 (zero-pad K 68->96) | wih_bf[2][128][128] bf16 |
// whh_h[2][128][128] fp16 | bsum[2][128] f32 (b_ih+b_hh)
__global__ __launch_bounds__(256) void k_prep(
    const float* __restrict__ wdyn,
    const float* __restrict__ wihf, const float* __restrict__ wihb,
    const float* __restrict__ whhf, const float* __restrict__ whhb,
    const float* __restrict__ bihf, const float* __restrict__ bhhf,
    const float* __restrict__ bihb, const float* __restrict__ bhhb,
    unsigned short* __restrict__ wdyn_bf, unsigned short* __restrict__ wih_bf,
    unsigned short* __restrict__ whh_h, float* __restrict__ bsum)
{
    int gid = blockIdx.x * 256 + threadIdx.x, gs = gridDim.x * 256;
    for (int i = gid; i < HD * 96; i += gs) {
        int r = i / 96, c = i - r * 96;
        wdyn_bf[i] = (c < DI) ? f2bf(wdyn[r * DI + c]) : 0;
    }
    for (int i = gid; i < 2 * HD * HD; i += gs) {
        const float* src = (i < HD * HD) ? wihf : wihb;
        wih_bf[i] = f2bf(src[i & (HD * HD - 1)]);
    }
    for (int i = gid; i < 2 * HD * HD; i += gs) {
        const float* src = (i < HD * HD) ? whhf : whhb;
        whh_h[i] = f2h(src[i & (HD * HD - 1)]);
    }
    for (int i = gid; i < 2 * HD; i += gs) {
        int z = i >> 7, n = i & (HD - 1);
        bsum[i] = z ? (bihb[n] + bhhb[n]) : (bihf[n] + bhhf[n]);
    }
}

// ---------------- K1: static branch + static segment of routed dot ----------
__global__ __launch_bounds__(256) void k_static(
    const float* __restrict__ xs_g, const float* __restrict__ w1,
    const float* __restrict__ b1, const float* __restrict__ w2,
    const float* __restrict__ b2, const int* __restrict__ norder,
    const float* __restrict__ nw, const float* __restrict__ nb,
    float* __restrict__ statd)
{
    __shared__ __align__(16) float xs[SI];
    __shared__ __align__(16) float s1[HS];
    __shared__ __align__(16) float red[256];
    int b = blockIdx.x, t = threadIdx.x;
    if (t < SI) xs[t] = xs_g[b * SI + t];
    __syncthreads();
    float a = b1[t];
    const float4* w = (const float4*)(w1 + t * SI);
    const float4* xp4 = (const float4*)xs;
    #pragma unroll
    for (int i = 0; i < SI / 4; ++i) {
        float4 ww = w[i]; float4 xx = xp4[i];
        a += xx.x * ww.x + xx.y * ww.y + xx.z * ww.z + xx.w * ww.w;
    }
    s1[t] = fmaxf(a, 0.f);
    __syncthreads();
    float a2 = b2[t];
    const float4* w2p = (const float4*)(w2 + t * HS);
    const float4* s1p = (const float4*)s1;
    #pragma unroll 8
    for (int i = 0; i < HS / 4; ++i) {
        float4 ww = w2p[i]; float4 s = s1p[i];
        a2 += s.x * ww.x + s.y * ww.y + s.z * ww.z + s.w * ww.w;
    }
    float sv = fmaxf(a2, 0.f);
    int n = norder[b];
    red[t] = sv * nw[(size_t)n * D + t];
    __syncthreads();
    for (int s = 128; s > 0; s >>= 1) {
        if (t < s) red[t] += red[t + s];
        __syncthreads();
    }
    if (t == 0) statd[b] = red[0] + nb[n];
}

// ---------------- K2: d + ih-projection via MFMA (operand-swapped) ----------
// A=weight rows n, B=activation rows batch -> C/D lane (ln,q) holds
// out[batch=w*16+ln][n=j*16+q*4+r], r=0..3 -> vector epilogues.
__global__ __launch_bounds__(256) void k_dxw(
    const float* __restrict__ xd,
    const unsigned short* __restrict__ wdyn_bf, const float* __restrict__ bdyn,
    const unsigned short* __restrict__ wih_bf, const float* __restrict__ bsum,
    unsigned short* __restrict__ xw)
{
    __shared__ __align__(16) unsigned short xb[64][104];  // x bf16, K 0..95 (+pad)
    __shared__ __align__(16) unsigned short dl[64][136];  // d bf16, 128 cols (+pad)
    int tid = threadIdx.x;
    int R0 = blockIdx.x * 64;
    // zero xb (vectorized 16B)
    for (int i = tid; i < 64 * 104 / 8; i += 256)
        ((uint4v*)xb)[i] = uint4v{0u, 0u, 0u, 0u};
    __syncthreads();
    // stage x: float4 loads, packed-bf16 b64 LDS writes (17 float4 per row)
    for (int i = tid; i < 64 * 17; i += 256) {
        int r = i / 17, c = i - r * 17;
        float4 v = *(const float4*)(xd + (size_t)(R0 + r) * DI + c * 4);
        uint2 pk;
        pk.x = pkbf(v.x, v.y);
        pk.y = pkbf(v.z, v.w);
        *(uint2*)&xb[r][c * 4] = pk;
    }
    __syncthreads();

    int lane = tid & 63, w = tid >> 6;
    int ln = lane & 15, q = lane >> 4;

    // ---- P2: A=wdyn[n][k], B=x[batch][k] ----
    short8 xf[3];
    #pragma unroll
    for (int c = 0; c < 3; ++c)
        xf[c] = *(const short8*)&xb[w * 16 + ln][c * 32 + q * 8];
    #pragma unroll
    for (int j = 0; j < 8; ++j) {
        floatx4 a = {0.f, 0.f, 0.f, 0.f};
        #pragma unroll
        for (int c = 0; c < 3; ++c) {
            short8 wf = *(const short8*)(wdyn_bf + (size_t)(j * 16 + ln) * 96 + c * 32 + q * 8);
            a = __builtin_amdgcn_mfma_f32_16x16x32_bf16(wf, xf[c], a, 0, 0, 0);
        }
        float4 bd4 = *(const float4*)(bdyn + j * 16 + q * 4);
        uint2 pk;
        pk.x = pkbf(fmaxf(a[0] + bd4.x, 0.f), fmaxf(a[1] + bd4.y, 0.f));
        pk.y = pkbf(fmaxf(a[2] + bd4.z, 0.f), fmaxf(a[3] + bd4.w, 0.f));
        *(uint2*)&dl[w * 16 + ln][j * 16 + q * 4] = pk;   // d[batch][n..n+3]
    }
    __syncthreads();

    // ---- P3 (both directions): A=wih[n][k], B=d[batch][k] ----
    short8 df[4];
    #pragma unroll
    for (int c = 0; c < 4; ++c)
        df[c] = *(const short8*)&dl[w * 16 + ln][c * 32 + q * 8];
    #pragma unroll
    for (int z = 0; z < 2; ++z) {
        const unsigned short* wih = wih_bf + (size_t)z * HD * HD;
        unsigned short* outp = xw + (size_t)z * BT * HD;
        int row = R0 + w * 16 + ln;
        #pragma unroll
        for (int j = 0; j < 8; ++j) {
            floatx4 a = {0.f, 0.f, 0.f, 0.f};
            #pragma unroll
            for (int c = 0; c < 4; ++c) {
                short8 wf = *(const short8*)(wih + (size_t)(j * 16 + ln) * HD + c * 32 + q * 8);
                a = __builtin_amdgcn_mfma_f32_16x16x32_bf16(wf, df[c], a, 0, 0, 0);
            }
            float4 b4 = *(const float4*)(bsum + z * HD + j * 16 + q * 4);
            uint2 hp;
            hp.x = (unsigned int)f2h(a[0] + b4.x) | ((unsigned int)f2h(a[1] + b4.y) << 16);
            hp.y = (unsigned int)f2h(a[2] + b4.z) | ((unsigned int)f2h(a[3] + b4.w) << 16);
            *(uint2*)(outp + (size_t)row * HD + j * 16 + q * 4) = hp;
        }
    }
}

// ---------------- K3: MFMA recurrence, 8-wave o-split -----------------------
// 64 blocks x 512 thr (8 waves). dir = bid>>5, b0 = (bid&31)*16.
// Wave w owns o-tile j=w: 4 MFMAs/step as 2 K-split depth-2 chains.
// D-frag -> B-frag handoff: one ds_write_b64 per lane (see header math).
__global__ __launch_bounds__(512, 1) void k_scan(
    const unsigned short* __restrict__ xw, const unsigned short* __restrict__ whh_h,
    const int* __restrict__ norder, const float* __restrict__ nw,
    float* __restrict__ accf, float* __restrict__ accb)
{
    __shared__ __align__(16) uint4v hxch[2][4][64];   // [parity][chunk][lane] 8KB

    int tid = threadIdx.x, w = tid >> 6, l = tid & 63, ln = l & 15, q = l >> 4;
    int dir = blockIdx.x >> 5, b0 = (blockIdx.x & 31) * 16;
    const unsigned short* whh = whh_h + (size_t)dir * HD * HD;
    float* acc = (dir ? accb : accf) + (size_t)w * BT;
    int segoff = dir ? (HS + HD) : HS;   // 384 : 256

    // A-frags: Whh[o = w*16+ln][k = c*32+q*8 .. +7], fp16
    half8 wfr[4];
    #pragma unroll
    for (int c = 0; c < 4; ++c)
        wfr[c] = *(const half8*)(whh + (size_t)(w * 16 + ln) * HD + c * 32 + q * 8);

    // routed weights for this wave's o-range (row=ln, o=w*16+q*4..+3)
    int nrow = norder[b0 + ln];
    float4 wnl = *(const float4*)(nw + (size_t)nrow * D + segoff + w * 16 + q * 4);

    // H_0 = 0
    half8 hf[4];
    uint4v zz = {0u, 0u, 0u, 0u};
    #pragma unroll
    for (int c = 0; c < 4; ++c) hf[c] = __builtin_bit_cast(half8, zz);

    const unsigned short* xp = xw + ((size_t)dir * BT + (size_t)(b0 + ln) * T) * HD
                               + w * 16 + q * 4;
    float* accp = acc + (size_t)(b0 + ln) * T;
    int tstart = dir ? (T - 1) : 0, dt = dir ? -1 : 1;

    // handoff write slot (constant per thread): chunk wc, quadrant qp, word m
    int wc = w >> 1;
    int qp = 2 * (w & 1) + (q >> 1);
    int boff = (q & 1) * 8;   // byte offset: words 2(q&1), 2(q&1)+1

    uint2 x0, x1, x2, x3;
    auto ld = [&](uint2& xb, int idx) {
        xb = *(const uint2*)(xp + (size_t)(tstart + dt * idx) * HD);
    };
    auto step = [&](uint2& xc, int idx) {
        int t = tstart + dt * idx;
        int par = idx & 1;
        // C-init: XW[batch ln][o=w*16+q*4..+3]
        half2t lo = u2h2(xc.x), hi = u2h2(xc.y);
        floatx4 a0 = {(float)lo[0], (float)lo[1], (float)hi[0], (float)hi[1]};
        floatx4 a1 = {0.f, 0.f, 0.f, 0.f};
        // 4 MFMAs: 2 independent K-split chains of depth 2
        a0 = __builtin_amdgcn_mfma_f32_16x16x32_f16(wfr[0], hf[0], a0, 0, 0, 0);
        a1 = __builtin_amdgcn_mfma_f32_16x16x32_f16(wfr[1], hf[1], a1, 0, 0, 0);
        a0 = __builtin_amdgcn_mfma_f32_16x16x32_f16(wfr[2], hf[2], a0, 0, 0, 0);
        a1 = __builtin_amdgcn_mfma_f32_16x16x32_f16(wfr[3], hf[3], a1, 0, 0, 0);
        floatx4 a = a0 + a1;
        // relu + pack; write D-words directly into B-frag slot (1 b64)
        float r0 = fmaxf(a[0], 0.f), r1 = fmaxf(a[1], 0.f);
        float r2 = fmaxf(a[2], 0.f), r3 = fmaxf(a[3], 0.f);
        uint2 hp;
        hp.x = pkh(r0, r1);
        hp.y = pkh(r2, r3);
        *(uint2*)((char*)&hxch[par][wc][qp * 16 + ln] + boff) = hp;
        // routed partial dot + q-reduce (2 permlane swaps), per-wave store
        float p = r0 * wnl.x + r1 * wnl.y + r2 * wnl.z + r3 * wnl.w;
        unsigned int pa = __builtin_bit_cast(unsigned int, p), pb = pa;
        pl32swap(pa, pb);
        float ps = __builtin_bit_cast(float, pa) + __builtin_bit_cast(float, pb);
        unsigned int pc = __builtin_bit_cast(unsigned int, ps), pd = pc;
        pl16swap(pc, pd);
        float ptot = __builtin_bit_cast(float, pc) + __builtin_bit_cast(float, pd);
        if (l < 16) accp[t] = ptot;
        // exchange: drain own DS write, raw barrier (NO vmcnt drain)
        asm volatile("s_waitcnt lgkmcnt(0)" ::: "memory");
        __builtin_amdgcn_sched_barrier(0);
        __builtin_amdgcn_s_barrier();
        __builtin_amdgcn_sched_barrier(0);
        #pragma unroll
        for (int c = 0; c < 4; ++c)
            hf[c] = __builtin_bit_cast(half8, hxch[par][c][l]);
    };

    ld(x0, 0); ld(x1, 1); ld(x2, 2); ld(x3, 3);
    for (int c = 0; c < T / 4 - 1; ++c) {
        int i0 = c * 4;
        step(x0, i0);     ld(x0, i0 + 4);
        step(x1, i0 + 1); ld(x1, i0 + 5);
        step(x2, i0 + 2); ld(x2, i0 + 6);
        step(x3, i0 + 3); ld(x3, i0 + 7);
    }
    step(x0, T - 4);
    step(x1, T - 3);
    step(x2, T - 2);
    step(x3, T - 1);
}

// ---------------- K4: out = relu(statd + sum of 8+8 partials) -> FP32 -------
__global__ __launch_bounds__(256) void k_final(
    const float* __restrict__ statd, const float* __restrict__ accf,
    const float* __restrict__ accb, float* __restrict__ out)
{
    int idx = blockIdx.x * 256 + threadIdx.x;
    if (idx < BT) {
        int b = idx / T;
        float s = statd[b];
        #pragma unroll
        for (int w = 0; w < 8; ++w)
            s += accf[(size_t)w * BT + idx] + accb[(size_t)w * BT + idx];
        out[idx] = fmaxf(s, 0.f);
    }
}

extern "C" void kernel_launch(void* const* d_in, const int* in_sizes, int n_in,
                              void* d_out, int out_size, void* d_ws, size_t ws_size,
                              hipStream_t stream)
{
    const float* x_static  = (const float*)d_in[0];
    const float* x_dynamic = (const float*)d_in[1];
    const int*   norder    = (const int*)d_in[2];
    const float* w_s1   = (const float*)d_in[3];
    const float* b_s1   = (const float*)d_in[4];
    const float* w_s2   = (const float*)d_in[5];
    const float* b_s2   = (const float*)d_in[6];
    const float* w_dyn  = (const float*)d_in[7];
    const float* b_dyn  = (const float*)d_in[8];
    const float* w_ih_f = (const float*)d_in[9];
    const float* w_hh_f = (const float*)d_in[10];
    const float* b_ih_f = (const float*)d_in[11];
    const float* b_hh_f = (const float*)d_in[12];
    const float* w_ih_b = (const float*)d_in[13];
    const float* w_hh_b = (const float*)d_in[14];
    const float* b_ih_b = (const float*)d_in[15];
    const float* b_hh_b = (const float*)d_in[16];
    const float* nw     = (const float*)d_in[17];
    const float* nb     = (const float*)d_in[18];
    float* out = (float*)d_out;

    // ws: statd 2KB | accf 8*BT*4 | accb 8*BT*4 | xw fp16 52.4MB | prepped wts
    char* ws = (char*)d_ws;
    float* statd = (float*)ws;
    float* accf  = (float*)(ws + 2048);
    float* accb  = (float*)(ws + 2048 + (size_t)8 * BT * 4);
    unsigned short* xw = (unsigned short*)(ws + 2048 + (size_t)16 * BT * 4);
    size_t xw_bytes = (size_t)2 * BT * HD * 2;   // 52.4 MB
    unsigned short* wdyn_bf = (unsigned short*)(ws + 2048 + (size_t)16 * BT * 4 + xw_bytes);
    unsigned short* wih_bf  = wdyn_bf + HD * 96;
    unsigned short* whh_h   = wih_bf + 2 * HD * HD;
    float* bsum = (float*)(whh_h + 2 * HD * HD);

    hipLaunchKernelGGL(k_prep, dim3(64), dim3(256), 0, stream,
                       w_dyn, w_ih_f, w_ih_b, w_hh_f, w_hh_b,
                       b_ih_f, b_hh_f, b_ih_b, b_hh_b,
                       wdyn_bf, wih_bf, whh_h, bsum);
    hipLaunchKernelGGL(k_static, dim3(B), dim3(256), 0, stream,
                       x_static, w_s1, b_s1, w_s2, b_s2, norder, nw, nb, statd);
    hipLaunchKernelGGL(k_dxw, dim3(BT / 64), dim3(256), 0, stream,
                       x_dynamic, wdyn_bf, b_dyn, wih_bf, bsum, xw);
    hipLaunchKernelGGL(k_scan, dim3(64), dim3(512), 0, stream,
                       xw, whh_h, norder, nw, accf, accb);
    hipLaunchKernelGGL(k_final, dim3((BT + 255) / 256), dim3(256), 0, stream,
                       statd, accf, accb, out);
}

// Round 11
// 244.463 us; speedup vs baseline: 1.4257x; 1.1380x over previous
//
#include <hip/hip_runtime.h>
#include <cstdint>

// MTNN: static MLP + dyn proj + biRNN(relu) + routed per-trial dot.
// B=512,T=200,SI=100,DI=68,HS=256,HD=128,D=512,K=1. fp32 in, fp32 out.
// R19 (passed, 278us): k_scan 8-wave o-split (4 MFMA/wave/step, ds_write_b64
// handoff) -> off top-5. k_dxw (80us) leads: NOT BW-bound (840 GB/s=13%),
// NOT MFMA-bound (4.3%) -- each of 1600 blocks re-reads all weights from L2
// (64 scattered wih loads + 24 wdyn loads per thread, ~500MB L2 traffic,
// dependent vmcnt waits inside the MFMA j-loops).
// R20: persistent k_dxw. 256 blocks (1/CU) grid-stride 1600 tiles; weight
// frags hoisted to VGPRs ONCE (wdyn 24 x half8 + wih 64 x half8 ~= 352
// VGPR, <450 no-spill @ 1 wave/SIMD). Inner loop = register MFMAs only;
// next tile's x-staging issued before P3 so HBM latency hides under MFMAs.
// xb K-pad zeroed once (staging overwrites only cols 0..67).
constexpr int B = 512, T = 200, SI = 100, DI = 68, HS = 256, HD = 128, D = 512;
constexpr int BT = B * T;   // 102400
constexpr int NT = BT / 64; // 1600 tiles

typedef __attribute__((ext_vector_type(8))) short short8;       // 8 bf16
typedef __attribute__((ext_vector_type(4))) float floatx4;      // MFMA C/D
typedef _Float16 half8 __attribute__((ext_vector_type(8)));     // 8 fp16
typedef _Float16 half2t __attribute__((ext_vector_type(2)));    // fp16 pair
typedef unsigned int uint2v __attribute__((ext_vector_type(2)));
typedef unsigned int uint4v __attribute__((ext_vector_type(4)));

#define DEV __device__ __forceinline__

DEV unsigned short f2bf(float f) {
    unsigned int x = __builtin_bit_cast(unsigned int, f);
    x += 0x7fffu + ((x >> 16) & 1u);   // RNE
    return (unsigned short)(x >> 16);
}
DEV unsigned int pkbf(float a, float b) {   // two bf16 in one dword
    return (unsigned int)f2bf(a) | ((unsigned int)f2bf(b) << 16);
}
DEV unsigned short f2h(float f) {
    return __builtin_bit_cast(unsigned short, (_Float16)f);
}
DEV half2t u2h2(unsigned int u) { return __builtin_bit_cast(half2t, u); }
DEV unsigned int pkh(float a, float b) {
    return __builtin_bit_cast(unsigned int, __builtin_amdgcn_cvt_pkrtz(a, b));
}
// gfx950 lane swaps (VALU), builtin form (SSA, no RA-coalescing hazard).
#if __has_builtin(__builtin_amdgcn_permlane32_swap) && __has_builtin(__builtin_amdgcn_permlane16_swap)
DEV void pl32swap(unsigned int& a, unsigned int& b) {
    uint2v r = __builtin_amdgcn_permlane32_swap(a, b, false, false);
    a = r[0]; b = r[1];
}
DEV void pl16swap(unsigned int& a, unsigned int& b) {
    uint2v r = __builtin_amdgcn_permlane16_swap(a, b, false, false);
    a = r[0]; b = r[1];
}
#else
DEV void pl32swap(unsigned int& a, unsigned int& b) {
    unsigned int na, nb;
    asm("v_mov_b32 %0, %2\n\t"
        "v_mov_b32 %1, %3\n\t"
        "v_permlane32_swap_b32 %0, %1"
        : "=&v"(na), "=&v"(nb) : "v"(a), "v"(b));
    a = na; b = nb;
}
DEV void pl16swap(unsigned int& a, unsigned int& b) {
    unsigned int na, nb;
    asm("v_mov_b32 %0, %2\n\t"
        "v_mov_b32 %1, %3\n\t"
        "v_permlane16_swap_b32 %0, %1"
        : "=&v"(na), "=&v"(nb) : "v"(a), "v"(b));
    a = na; b = nb;
}
#endif

// ---------------- K0: one-time weight conversion ----------------------------
// wdyn_bf[128][96] bf16 (zero-pad K 68->96) | wih_bf[2][128][128] bf16 |
// whh_h[2][128][128] fp16 | bsum[2][128] f32 (b_ih+b_hh)
__global__ __launch_bounds__(256) void k_prep(
    const float* __restrict__ wdyn,
    const float* __restrict__ wihf, const float* __restrict__ wihb,
    const float* __restrict__ whhf, const float* __restrict__ whhb,
    const float* __restrict__ bihf, const float* __restrict__ bhhf,
    const float* __restrict__ bihb, const float* __restrict__ bhhb,
    unsigned short* __restrict__ wdyn_bf, unsigned short* __restrict__ wih_bf,
    unsigned short* __restrict__ whh_h, float* __restrict__ bsum)
{
    int gid = blockIdx.x * 256 + threadIdx.x, gs = gridDim.x * 256;
    for (int i = gid; i < HD * 96; i += gs) {
        int r = i / 96, c = i - r * 96;
        wdyn_bf[i] = (c < DI) ? f2bf(wdyn[r * DI + c]) : 0;
    }
    for (int i = gid; i < 2 * HD * HD; i += gs) {
        const float* src = (i < HD * HD) ? wihf : wihb;
        wih_bf[i] = f2bf(src[i & (HD * HD - 1)]);
    }
    for (int i = gid; i < 2 * HD * HD; i += gs) {
        const float* src = (i < HD * HD) ? whhf : whhb;
        whh_h[i] = f2h(src[i & (HD * HD - 1)]);
    }
    for (int i = gid; i < 2 * HD; i += gs) {
        int z = i >> 7, n = i & (HD - 1);
        bsum[i] = z ? (bihb[n] + bhhb[n]) : (bihf[n] + bhhf[n]);
    }
}

// ---------------- K1: static branch + static segment of routed dot ----------
__global__ __launch_bounds__(256) void k_static(
    const float* __restrict__ xs_g, const float* __restrict__ w1,
    const float* __restrict__ b1, const float* __restrict__ w2,
    const float* __restrict__ b2, const int* __restrict__ norder,
    const float* __restrict__ nw, const float* __restrict__ nb,
    float* __restrict__ statd)
{
    __shared__ __align__(16) float xs[SI];
    __shared__ __align__(16) float s1[HS];
    __shared__ __align__(16) float red[256];
    int b = blockIdx.x, t = threadIdx.x;
    if (t < SI) xs[t] = xs_g[b * SI + t];
    __syncthreads();
    float a = b1[t];
    const float4* w = (const float4*)(w1 + t * SI);
    const float4* xp4 = (const float4*)xs;
    #pragma unroll
    for (int i = 0; i < SI / 4; ++i) {
        float4 ww = w[i]; float4 xx = xp4[i];
        a += xx.x * ww.x + xx.y * ww.y + xx.z * ww.z + xx.w * ww.w;
    }
    s1[t] = fmaxf(a, 0.f);
    __syncthreads();
    float a2 = b2[t];
    const float4* w2p = (const float4*)(w2 + t * HS);
    const float4* s1p = (const float4*)s1;
    #pragma unroll 8
    for (int i = 0; i < HS / 4; ++i) {
        float4 ww = w2p[i]; float4 s = s1p[i];
        a2 += s.x * ww.x + s.y * ww.y + s.z * ww.z + s.w * ww.w;
    }
    float sv = fmaxf(a2, 0.f);
    int n = norder[b];
    red[t] = sv * nw[(size_t)n * D + t];
    __syncthreads();
    for (int s = 128; s > 0; s >>= 1) {
        if (t < s) red[t] += red[t + s];
        __syncthreads();
    }
    if (t == 0) statd[b] = red[0] + nb[n];
}

// ---------------- K2: persistent d + ih-projection (weights in VGPRs) -------
// 256 blocks grid-stride over 1600 tiles. A=weight rows n, B=activation rows
// batch -> C/D lane (ln,q) holds out[batch=w*16+ln][n=j*16+q*4+r].
__global__ __launch_bounds__(256, 1) void k_dxw(
    const float* __restrict__ xd,
    const unsigned short* __restrict__ wdyn_bf, const float* __restrict__ bdyn,
    const unsigned short* __restrict__ wih_bf, const float* __restrict__ bsum,
    unsigned short* __restrict__ xw)
{
    __shared__ __align__(16) unsigned short xb[64][104];  // x bf16, K 0..95 (+pad)
    __shared__ __align__(16) unsigned short dl[64][136];  // d bf16, 128 cols (+pad)
    int tid = threadIdx.x;
    int lane = tid & 63, w = tid >> 6;
    int ln = lane & 15, q = lane >> 4;

    // hoist ALL weight fragments to registers (per-thread, reused all tiles)
    short8 wdf[8][3];        // wdyn: 96 VGPR
    #pragma unroll
    for (int j = 0; j < 8; ++j)
        #pragma unroll
        for (int c = 0; c < 3; ++c)
            wdf[j][c] = *(const short8*)(wdyn_bf + (size_t)(j * 16 + ln) * 96 + c * 32 + q * 8);
    short8 wif[2][8][4];     // wih both dirs: 256 VGPR
    #pragma unroll
    for (int z = 0; z < 2; ++z)
        #pragma unroll
        for (int j = 0; j < 8; ++j)
            #pragma unroll
            for (int c = 0; c < 4; ++c)
                wif[z][j][c] = *(const short8*)(wih_bf + (size_t)z * HD * HD +
                    (size_t)(j * 16 + ln) * HD + c * 32 + q * 8);

    // zero xb once: staging only overwrites cols 0..67, pad stays 0
    for (int i = tid; i < 64 * 104 / 8; i += 256)
        ((uint4v*)xb)[i] = uint4v{0u, 0u, 0u, 0u};

    auto stage = [&](int tile) {
        int R0 = tile * 64;
        for (int i = tid; i < 64 * 17; i += 256) {
            int r = i / 17, c = i - r * 17;
            float4 v = *(const float4*)(xd + (size_t)(R0 + r) * DI + c * 4);
            uint2 pk;
            pk.x = pkbf(v.x, v.y);
            pk.y = pkbf(v.z, v.w);
            *(uint2*)&xb[r][c * 4] = pk;
        }
    };

    stage(blockIdx.x);
    __syncthreads();

    for (int tile = blockIdx.x; tile < NT; tile += gridDim.x) {
        int R0 = tile * 64;
        // ---- P2: d = relu(x @ Wdyn^T + b) -> dl ----
        short8 xf[3];
        #pragma unroll
        for (int c = 0; c < 3; ++c)
            xf[c] = *(const short8*)&xb[w * 16 + ln][c * 32 + q * 8];
        #pragma unroll
        for (int j = 0; j < 8; ++j) {
            floatx4 a = {0.f, 0.f, 0.f, 0.f};
            #pragma unroll
            for (int c = 0; c < 3; ++c)
                a = __builtin_amdgcn_mfma_f32_16x16x32_bf16(wdf[j][c], xf[c], a, 0, 0, 0);
            float4 bd4 = *(const float4*)(bdyn + j * 16 + q * 4);
            uint2 pk;
            pk.x = pkbf(fmaxf(a[0] + bd4.x, 0.f), fmaxf(a[1] + bd4.y, 0.f));
            pk.y = pkbf(fmaxf(a[2] + bd4.z, 0.f), fmaxf(a[3] + bd4.w, 0.f));
            *(uint2*)&dl[w * 16 + ln][j * 16 + q * 4] = pk;
        }
        __syncthreads();

        // ---- P3: xw = d @ Wih^T + bsum (both dirs); prefetch next x ----
        int nxt = tile + gridDim.x;
        if (nxt < NT) stage(nxt);   // writes xb (P2 done for all waves)
        short8 df[4];
        #pragma unroll
        for (int c = 0; c < 4; ++c)
            df[c] = *(const short8*)&dl[w * 16 + ln][c * 32 + q * 8];
        int row = R0 + w * 16 + ln;
        #pragma unroll
        for (int z = 0; z < 2; ++z) {
            unsigned short* outp = xw + (size_t)z * BT * HD;
            #pragma unroll
            for (int j = 0; j < 8; ++j) {
                floatx4 a = {0.f, 0.f, 0.f, 0.f};
                #pragma unroll
                for (int c = 0; c < 4; ++c)
                    a = __builtin_amdgcn_mfma_f32_16x16x32_bf16(wif[z][j][c], df[c], a, 0, 0, 0);
                float4 b4 = *(const float4*)(bsum + z * HD + j * 16 + q * 4);
                uint2 hp;
                hp.x = (unsigned int)f2h(a[0] + b4.x) | ((unsigned int)f2h(a[1] + b4.y) << 16);
                hp.y = (unsigned int)f2h(a[2] + b4.z) | ((unsigned int)f2h(a[3] + b4.w) << 16);
                *(uint2*)(outp + (size_t)row * HD + j * 16 + q * 4) = hp;
            }
        }
        __syncthreads();
    }
}

// ---------------- K3: MFMA recurrence, 8-wave o-split -----------------------
// 64 blocks x 512 thr (8 waves). dir = bid>>5, b0 = (bid&31)*16.
// Wave w owns o-tile j=w: 4 MFMAs/step as 2 K-split depth-2 chains.
// D-frag -> B-frag handoff: one ds_write_b64 per lane.
__global__ __launch_bounds__(512, 1) void k_scan(
    const unsigned short* __restrict__ xw, const unsigned short* __restrict__ whh_h,
    const int* __restrict__ norder, const float* __restrict__ nw,
    float* __restrict__ accf, float* __restrict__ accb)
{
    __shared__ __align__(16) uint4v hxch[2][4][64];   // [parity][chunk][lane] 8KB

    int tid = threadIdx.x, w = tid >> 6, l = tid & 63, ln = l & 15, q = l >> 4;
    int dir = blockIdx.x >> 5, b0 = (blockIdx.x & 31) * 16;
    const unsigned short* whh = whh_h + (size_t)dir * HD * HD;
    float* acc = (dir ? accb : accf) + (size_t)w * BT;
    int segoff = dir ? (HS + HD) : HS;   // 384 : 256

    // A-frags: Whh[o = w*16+ln][k = c*32+q*8 .. +7], fp16
    half8 wfr[4];
    #pragma unroll
    for (int c = 0; c < 4; ++c)
        wfr[c] = *(const half8*)(whh + (size_t)(w * 16 + ln) * HD + c * 32 + q * 8);

    // routed weights for this wave's o-range (row=ln, o=w*16+q*4..+3)
    int nrow = norder[b0 + ln];
    float4 wnl = *(const float4*)(nw + (size_t)nrow * D + segoff + w * 16 + q * 4);

    // H_0 = 0
    half8 hf[4];
    uint4v zz = {0u, 0u, 0u, 0u};
    #pragma unroll
    for (int c = 0; c < 4; ++c) hf[c] = __builtin_bit_cast(half8, zz);

    const unsigned short* xp = xw + ((size_t)dir * BT + (size_t)(b0 + ln) * T) * HD
                               + w * 16 + q * 4;
    float* accp = acc + (size_t)(b0 + ln) * T;
    int tstart = dir ? (T - 1) : 0, dt = dir ? -1 : 1;

    // handoff write slot (constant per thread): chunk wc, quadrant qp, word m
    int wc = w >> 1;
    int qp = 2 * (w & 1) + (q >> 1);
    int boff = (q & 1) * 8;   // byte offset: words 2(q&1), 2(q&1)+1

    uint2 x0, x1, x2, x3;
    auto ld = [&](uint2& xb, int idx) {
        xb = *(const uint2*)(xp + (size_t)(tstart + dt * idx) * HD);
    };
    auto step = [&](uint2& xc, int idx) {
        int t = tstart + dt * idx;
        int par = idx & 1;
        // C-init: XW[batch ln][o=w*16+q*4..+3]
        half2t lo = u2h2(xc.x), hi = u2h2(xc.y);
        floatx4 a0 = {(float)lo[0], (float)lo[1], (float)hi[0], (float)hi[1]};
        floatx4 a1 = {0.f, 0.f, 0.f, 0.f};
        // 4 MFMAs: 2 independent K-split chains of depth 2
        a0 = __builtin_amdgcn_mfma_f32_16x16x32_f16(wfr[0], hf[0], a0, 0, 0, 0);
        a1 = __builtin_amdgcn_mfma_f32_16x16x32_f16(wfr[1], hf[1], a1, 0, 0, 0);
        a0 = __builtin_amdgcn_mfma_f32_16x16x32_f16(wfr[2], hf[2], a0, 0, 0, 0);
        a1 = __builtin_amdgcn_mfma_f32_16x16x32_f16(wfr[3], hf[3], a1, 0, 0, 0);
        floatx4 a = a0 + a1;
        // relu + pack; write D-words directly into B-frag slot (1 b64)
        float r0 = fmaxf(a[0], 0.f), r1 = fmaxf(a[1], 0.f);
        float r2 = fmaxf(a[2], 0.f), r3 = fmaxf(a[3], 0.f);
        uint2 hp;
        hp.x = pkh(r0, r1);
        hp.y = pkh(r2, r3);
        *(uint2*)((char*)&hxch[par][wc][qp * 16 + ln] + boff) = hp;
        // routed partial dot + q-reduce (2 permlane swaps), per-wave store
        float p = r0 * wnl.x + r1 * wnl.y + r2 * wnl.z + r3 * wnl.w;
        unsigned int pa = __builtin_bit_cast(unsigned int, p), pb = pa;
        pl32swap(pa, pb);
        float ps = __builtin_bit_cast(float, pa) + __builtin_bit_cast(float, pb);
        unsigned int pc = __builtin_bit_cast(unsigned int, ps), pd = pc;
        pl16swap(pc, pd);
        float ptot = __builtin_bit_cast(float, pc) + __builtin_bit_cast(float, pd);
        if (l < 16) accp[t] = ptot;
        // exchange: drain own DS write, raw barrier (NO vmcnt drain)
        asm volatile("s_waitcnt lgkmcnt(0)" ::: "memory");
        __builtin_amdgcn_sched_barrier(0);
        __builtin_amdgcn_s_barrier();
        __builtin_amdgcn_sched_barrier(0);
        #pragma unroll
        for (int c = 0; c < 4; ++c)
            hf[c] = __builtin_bit_cast(half8, hxch[par][c][l]);
    };

    ld(x0, 0); ld(x1, 1); ld(x2, 2); ld(x3, 3);
    for (int c = 0; c < T / 4 - 1; ++c) {
        int i0 = c * 4;
        step(x0, i0);     ld(x0, i0 + 4);
        step(x1, i0 + 1); ld(x1, i0 + 5);
        step(x2, i0 + 2); ld(x2, i0 + 6);
        step(x3, i0 + 3); ld(x3, i0 + 7);
    }
    step(x0, T - 4);
    step(x1, T - 3);
    step(x2, T - 2);
    step(x3, T - 1);
}

// ---------------- K4: out = relu(statd + sum of 8+8 partials) -> FP32 -------
__global__ __launch_bounds__(256) void k_final(
    const float* __restrict__ statd, const float* __restrict__ accf,
    const float* __restrict__ accb, float* __restrict__ out)
{
    int idx = blockIdx.x * 256 + threadIdx.x;
    if (idx < BT) {
        int b = idx / T;
        float s = statd[b];
        #pragma unroll
        for (int w = 0; w < 8; ++w)
            s += accf[(size_t)w * BT + idx] + accb[(size_t)w * BT + idx];
        out[idx] = fmaxf(s, 0.f);
    }
}

extern "C" void kernel_launch(void* const* d_in, const int* in_sizes, int n_in,
                              void* d_out, int out_size, void* d_ws, size_t ws_size,
                              hipStream_t stream)
{
    const float* x_static  = (const float*)d_in[0];
    const float* x_dynamic = (const float*)d_in[1];
    const int*   norder    = (const int*)d_in[2];
    const float* w_s1   = (const float*)d_in[3];
    const float* b_s1   = (const float*)d_in[4];
    const float* w_s2   = (const float*)d_in[5];
    const float* b_s2   = (const float*)d_in[6];
    const float* w_dyn  = (const float*)d_in[7];
    const float* b_dyn  = (const float*)d_in[8];
    const float* w_ih_f = (const float*)d_in[9];
    const float* w_hh_f = (const float*)d_in[10];
    const float* b_ih_f = (const float*)d_in[11];
    const float* b_hh_f = (const float*)d_in[12];
    const float* w_ih_b = (const float*)d_in[13];
    const float* w_hh_b = (const float*)d_in[14];
    const float* b_ih_b = (const float*)d_in[15];
    const float* b_hh_b = (const float*)d_in[16];
    const float* nw     = (const float*)d_in[17];
    const float* nb     = (const float*)d_in[18];
    float* out = (float*)d_out;

    // ws: statd 2KB | accf 8*BT*4 | accb 8*BT*4 | xw fp16 52.4MB | prepped wts
    char* ws = (char*)d_ws;
    float* statd = (float*)ws;
    float* accf  = (float*)(ws + 2048);
    float* accb  = (float*)(ws + 2048 + (size_t)8 * BT * 4);
    unsigned short* xw = (unsigned short*)(ws + 2048 + (size_t)16 * BT * 4);
    size_t xw_bytes = (size_t)2 * BT * HD * 2;   // 52.4 MB
    unsigned short* wdyn_bf = (unsigned short*)(ws + 2048 + (size_t)16 * BT * 4 + xw_bytes);
    unsigned short* wih_bf  = wdyn_bf + HD * 96;
    unsigned short* whh_h   = wih_bf + 2 * HD * HD;
    float* bsum = (float*)(whh_h + 2 * HD * HD);

    hipLaunchKernelGGL(k_prep, dim3(64), dim3(256), 0, stream,
                       w_dyn, w_ih_f, w_ih_b, w_hh_f, w_hh_b,
                       b_ih_f, b_hh_f, b_ih_b, b_hh_b,
                       wdyn_bf, wih_bf, whh_h, bsum);
    hipLaunchKernelGGL(k_static, dim3(B), dim3(256), 0, stream,
                       x_static, w_s1, b_s1, w_s2, b_s2, norder, nw, nb, statd);
    hipLaunchKernelGGL(k_dxw, dim3(256), dim3(256), 0, stream,
                       x_dynamic, wdyn_bf, b_dyn, wih_bf, bsum, xw);
    hipLaunchKernelGGL(k_scan, dim3(64), dim3(512), 0, stream,
                       xw, whh_h, norder, nw, accf, accb);
    hipLaunchKernelGGL(k_final, dim3((BT + 255) / 256), dim3(256), 0, stream,
                       statd, accf, accb, out);
}